// Round 5
// baseline (287.001 us; speedup 1.0000x reference)
//
#include <hip/hip_runtime.h>

#define BB 64
#define TT 16384
#define EE 512

// partial-plane: Xq part (192*512) + Xkv part (256*1024) = 360448 floats
#define PSZ 360448
#define PQ_OFF 98304

typedef _Float16 half8 __attribute__((ext_vector_type(8)));
typedef float floatx4 __attribute__((ext_vector_type(4)));

static __device__ __forceinline__ half8 cvt_half8(float4 a, float4 b) {
  half8 h;
  h[0] = (_Float16)a.x; h[1] = (_Float16)a.y; h[2] = (_Float16)a.z; h[3] = (_Float16)a.w;
  h[4] = (_Float16)b.x; h[5] = (_Float16)b.y; h[6] = (_Float16)b.z; h[7] = (_Float16)b.w;
  return h;
}

// global -> LDS direct staging, 16B per lane. LDS dest is wave-uniform base +
// lane*16 (hardware); global src is per-lane (XOR swizzle applied on the
// SOURCE, LDS stays linear -- m173 pattern).
static __device__ __forceinline__ void gload_lds16(const void* g, void* l) {
  __builtin_amdgcn_global_load_lds(
      (const __attribute__((address_space(1))) void*)g,
      (__attribute__((address_space(3))) void*)l, 16, 0, 0);
}

// ---------------------------------------------------------------------------
// Stage 1 v6: NO ATOMICS. R4 post-mortem: three different sync structures
// (R0/R3/R4) all hit the same ~90us with the same 11.5M device-scope fp32
// atomicAdds and WRITE_SIZE==45MB==11.5M*4B (every atomic written through to
// the memory side -- per-XCD L2s aren't coherent, so device atomics RMW at
// the shared level; ~128G RMW/s == 90us floor). Reads changed 540->721MB
// between R0/R4 with zero time change -> reads not binding; atomics are.
// Fix: split-K partials to DISTINCT planes (plain coalesced stores, 23MB),
// tiny reduce kernel sums CH planes. zero_ws dropped (all ws fully written).
// Tiles 64x128 (cuts staging reads 721->553MB): 12 Xq + 32 Xkv = 44 tiles
// x CH chunks. Main loop: validated R4 pipeline (3 LDS bufs, counted
// vmcnt(6), raw s_barrier + sched_barrier, setprio around MFMA).
// ---------------------------------------------------------------------------
__global__ __launch_bounds__(256) void proj_gemm(
    const float* __restrict__ x, const float* __restrict__ Wq,
    const float* __restrict__ Wk, const float* __restrict__ Wv,
    float* __restrict__ P, int KL, int NT, int cpx)
{
  __shared__ float Abuf[3][64 * 32];    // 8 KB each
  __shared__ float Bbuf[3][128 * 32];   // 16 KB each  (72 KB total)
  const int t = threadIdx.x;
  const int wave = t >> 6, lane = t & 63;
  const int quad = lane >> 4, l16 = lane & 15;
  const int wr = wave >> 1, wc = wave & 1;     // 2x2 wave grid, wave=32x64

  // XCD-affinity (bijective: nblocks = 8*cpx)
  const int orig = blockIdx.x;
  const int logical = (orig & 7) * cpx + (orig >> 3);
  const int chunk = logical / 44;
  const int tile  = logical - chunk * 44;
  const int k0 = chunk * KL;

  int mtile, ntile, cpb, chan_base;
  const float* Wsrc;
  int pbase;                                   // plane-local output base
  if (tile < 12) {                             // Xq: 3m x 4n of 128
    mtile = tile >> 2; ntile = tile & 3;
    cpb = 3; chan_base = 0;
    Wsrc = Wq + (size_t)(ntile * 128) * TT;
    pbase = 0;
  } else {                                     // Xkv: 4m x 8n of 128
    const int t2 = tile - 12;
    mtile = t2 >> 3; ntile = t2 & 7;
    cpb = 4; chan_base = 3;
    Wsrc = (ntile < 4) ? (Wk + (size_t)(ntile * 128) * TT)
                       : (Wv + (size_t)((ntile - 4) * 128) * TT);
    pbase = PQ_OFF;
  }
  const int ldout = (tile < 12) ? 512 : 1024;

  // staging sources. A: 512 16B-units (2 rounds), B: 1024 units (4 rounds).
  // round r: unit i = (r*4+wave)*64+lane; row = i>>3; u = i&7;
  // source unit = u ^ (row&7)  (swizzle source-side, LDS linear)
  const float* aSrc[2];
  const float* bSrc[4];
#pragma unroll
  for (int r = 0; r < 2; ++r) {
    const int i = (r * 4 + wave) * 64 + lane;
    const int row = i >> 3, u = i & 7;
    const int m = mtile * 64 + row;
    const int bidx = (cpb == 3) ? ((m * 21846) >> 16) : (m >> 2);
    const int j = m - bidx * cpb;
    aSrc[r] = x + (size_t)(bidx * 7 + chan_base + j) * TT + k0
                + ((u ^ (row & 7)) << 2);
  }
#pragma unroll
  for (int r = 0; r < 4; ++r) {
    const int i = (r * 4 + wave) * 64 + lane;
    const int row = i >> 3, u = i & 7;
    bSrc[r] = Wsrc + (size_t)row * TT + k0 + ((u ^ (row & 7)) << 2);
  }

  floatx4 acc[2][4];
#pragma unroll
  for (int rt = 0; rt < 2; ++rt)
#pragma unroll
    for (int ct = 0; ct < 4; ++ct)
      acc[rt][ct] = (floatx4){0.f, 0.f, 0.f, 0.f};

  auto stage = [&](int kt_, int buf_) {        // 6 gloads / thread / tile
    const int ko = kt_ * 32;
#pragma unroll
    for (int r = 0; r < 2; ++r)
      gload_lds16(aSrc[r] + ko, &Abuf[buf_][(r * 4 + wave) * 256]);
#pragma unroll
    for (int r = 0; r < 4; ++r)
      gload_lds16(bSrc[r] + ko, &Bbuf[buf_][(r * 4 + wave) * 256]);
  };
  auto compute = [&](int buf_) {
    half8 hb[4], ha[2];
#pragma unroll
    for (int ct = 0; ct < 4; ++ct) {
      const int brow = wc * 64 + ct * 16 + l16;
      const int sw = brow & 7;
      float4 b0 = *(const float4*)&Bbuf[buf_][brow * 32 + ((((quad << 1) | 0) ^ sw) << 2)];
      float4 b1 = *(const float4*)&Bbuf[buf_][brow * 32 + ((((quad << 1) | 1) ^ sw) << 2)];
      hb[ct] = cvt_half8(b0, b1);
    }
#pragma unroll
    for (int rt = 0; rt < 2; ++rt) {
      const int arow = wr * 32 + rt * 16 + l16;
      const int sw = arow & 7;
      float4 a0 = *(const float4*)&Abuf[buf_][arow * 32 + ((((quad << 1) | 0) ^ sw) << 2)];
      float4 a1 = *(const float4*)&Abuf[buf_][arow * 32 + ((((quad << 1) | 1) ^ sw) << 2)];
      ha[rt] = cvt_half8(a0, a1);
    }
    __builtin_amdgcn_s_setprio(1);
#pragma unroll
    for (int rt = 0; rt < 2; ++rt)
#pragma unroll
      for (int ct = 0; ct < 4; ++ct)
        acc[rt][ct] = __builtin_amdgcn_mfma_f32_16x16x32_f16(ha[rt], hb[ct], acc[rt][ct], 0, 0, 0);
    __builtin_amdgcn_s_setprio(0);
  };

  // prologue: 2 tiles in flight; wait only the oldest
  stage(0, 0);
  stage(1, 1);
  asm volatile("s_waitcnt vmcnt(6)" ::: "memory");
  __builtin_amdgcn_s_barrier();
  __builtin_amdgcn_sched_barrier(0);

  int cur = 0;
  for (int kt = 0; kt < NT - 2; ++kt) {
    const int nx2 = (cur + 2 >= 3) ? cur - 1 : cur + 2;   // (kt+2)%3
    stage(kt + 2, nx2);
    compute(cur);
    asm volatile("s_waitcnt vmcnt(6)" ::: "memory");      // kt+1 ready; kt+2 in flight
    __builtin_amdgcn_s_barrier();
    __builtin_amdgcn_sched_barrier(0);
    cur = (cur + 1 >= 3) ? 0 : cur + 1;
  }
  compute(cur);
  asm volatile("s_waitcnt vmcnt(0)" ::: "memory");        // tail drain
  __builtin_amdgcn_s_barrier();
  __builtin_amdgcn_sched_barrier(0);
  compute((cur + 1 >= 3) ? 0 : cur + 1);

  // epilogue: PLAIN stores into this chunk's partial plane.
  // C/D layout col=lane&15, row=quad*4+reg
  float* outP = P + (size_t)chunk * PSZ + pbase;
#pragma unroll
  for (int rt = 0; rt < 2; ++rt) {
#pragma unroll
    for (int ct = 0; ct < 4; ++ct) {
      const int gr = mtile * 64 + wr * 32 + rt * 16 + quad * 4;
      const int gc = ntile * 128 + wc * 64 + ct * 16 + l16;
#pragma unroll
      for (int rg = 0; rg < 4; ++rg)
        outP[(size_t)(gr + rg) * ldout + gc] = acc[rt][ct][rg];
    }
  }
}

// ---------------------------------------------------------------------------
// Reduce CH partial planes -> Xq / Xkv. 352 blocks x 256 thr x 1 float4
// = 90112 float4 = 360448 floats, exactly one plane.
// ---------------------------------------------------------------------------
__global__ __launch_bounds__(256) void reduce_p(
    const floatx4* __restrict__ P4, float* __restrict__ Xq,
    float* __restrict__ Xkv, int CH)
{
  const int i = blockIdx.x * 256 + threadIdx.x;   // 0..90111
  floatx4 s = P4[i];
  for (int c = 1; c < CH; ++c) s += P4[(size_t)c * (PSZ / 4) + i];
  if (i < PQ_OFF / 4) ((floatx4*)Xq)[i] = s;
  else                ((floatx4*)Xkv)[i - PQ_OFF / 4] = s;
}

// ---------------------------------------------------------------------------
// Stage 2: per (batch, 64-wide e-chunk): build K(16x512), VW(3x512), Q(16x64)
// in LDS, then per e-row: S = 0.25*Q^T K, softmax over f, u[o,e]=P·VW[o]/den.
// (unchanged -- verified correct)
// ---------------------------------------------------------------------------
__global__ __launch_bounds__(256) void attn_mid(
    const float* __restrict__ Xq, const float* __restrict__ Xkv,
    const float* __restrict__ W1, const float* __restrict__ W2,
    const float* __restrict__ W3,
    const float* __restrict__ bq, const float* __restrict__ bk,
    const float* __restrict__ bv, _Float16* __restrict__ U)
{
  __shared__ float Ks[16][512];
  __shared__ float VW[3][512];
  __shared__ float Qs[16][64];
  __shared__ float Xs[4][512];
  __shared__ float W1s[48], W2s[64], W3s[48], W32s[12], w3sum[3];
  const int t = threadIdx.x;
  const int b = blockIdx.y;
  const int e0 = blockIdx.x * 64;

  if (t < 48) W1s[t] = W1[t];
  if (t >= 64 && t < 128) W2s[t - 64] = W2[t - 64];
  if (t >= 128 && t < 176) W3s[t - 128] = W3[t - 128];
  __syncthreads();
  if (t < 12) {                       // W32[o][j] = sum_c W3[o][c]*W2[c][j]
    const int o = t >> 2, jj = t & 3;
    float s = 0.f;
    for (int c = 0; c < 16; ++c) s += W3s[o * 16 + c] * W2s[c * 4 + jj];
    W32s[t] = s;
  }
  if (t >= 16 && t < 19) {
    const int o = t - 16;
    float s = 0.f;
    for (int c = 0; c < 16; ++c) s += W3s[o * 16 + c];
    w3sum[o] = s;
  }
  // stage Xk, build K
  for (int i = t; i < 2048; i += 256) {
    const int jj = i >> 9, f = i & 511;
    Xs[jj][f] = Xkv[(size_t)(b * 4 + jj) * 1024 + f];
  }
  __syncthreads();
  for (int i = t; i < 8192; i += 256) {
    const int c = i >> 9, f = i & 511;
    float s = bk[f];
#pragma unroll
    for (int jj = 0; jj < 4; ++jj) s += W2s[c * 4 + jj] * Xs[jj][f];
    Ks[c][f] = s;
  }
  __syncthreads();
  // stage Xv, build VW
  for (int i = t; i < 2048; i += 256) {
    const int jj = i >> 9, f = i & 511;
    Xs[jj][f] = Xkv[(size_t)(b * 4 + jj) * 1024 + 512 + f];
  }
  __syncthreads();
  for (int i = t; i < 1536; i += 256) {
    const int o = i >> 9, f = i & 511;
    float s = w3sum[o] * bv[f];
#pragma unroll
    for (int jj = 0; jj < 4; ++jj) s += W32s[o * 4 + jj] * Xs[jj][f];
    VW[o][f] = s;
  }
  // build Q for this e-chunk
  for (int i = t; i < 1024; i += 256) {
    const int c = i >> 6, el = i & 63;
    float s = bq[e0 + el];
#pragma unroll
    for (int jj = 0; jj < 3; ++jj)
      s += W1s[c * 3 + jj] * Xq[(size_t)(b * 3 + jj) * 512 + e0 + el];
    Qs[c][el] = s;
  }
  __syncthreads();

  const int wave = t >> 6, lane = t & 63;
  float vwr[3][8];
#pragma unroll
  for (int o = 0; o < 3; ++o) {
    float4 va = *(const float4*)&VW[o][lane * 8];
    float4 vb = *(const float4*)&VW[o][lane * 8 + 4];
    vwr[o][0] = va.x; vwr[o][1] = va.y; vwr[o][2] = va.z; vwr[o][3] = va.w;
    vwr[o][4] = vb.x; vwr[o][5] = vb.y; vwr[o][6] = vb.z; vwr[o][7] = vb.w;
  }

  for (int g = 0; g < 4; ++g) {       // 4 groups of 4 e-rows per wave
    const int el0 = wave * 16 + g * 4;
    float s[4][8];
#pragma unroll
    for (int e = 0; e < 4; ++e)
#pragma unroll
      for (int i = 0; i < 8; ++i) s[e][i] = 0.f;
#pragma unroll
    for (int c = 0; c < 16; ++c) {
      float4 k0 = *(const float4*)&Ks[c][lane * 8];
      float4 k1 = *(const float4*)&Ks[c][lane * 8 + 4];
      float4 qv = *(const float4*)&Qs[c][el0];
      float qa[4] = {qv.x, qv.y, qv.z, qv.w};
#pragma unroll
      for (int e = 0; e < 4; ++e) {
        const float q = qa[e];
        s[e][0] += q * k0.x; s[e][1] += q * k0.y; s[e][2] += q * k0.z; s[e][3] += q * k0.w;
        s[e][4] += q * k1.x; s[e][5] += q * k1.y; s[e][6] += q * k1.z; s[e][7] += q * k1.w;
      }
    }
#pragma unroll
    for (int e = 0; e < 4; ++e) {
      float mx = s[e][0];
#pragma unroll
      for (int i = 1; i < 8; ++i) mx = fmaxf(mx, s[e][i]);
#pragma unroll
      for (int off = 32; off; off >>= 1) mx = fmaxf(mx, __shfl_xor(mx, off));
      float p[8], sum = 0.f;
#pragma unroll
      for (int i = 0; i < 8; ++i) { p[i] = __expf(0.25f * (s[e][i] - mx)); sum += p[i]; }
      float u0 = 0.f, u1 = 0.f, u2 = 0.f;
#pragma unroll
      for (int i = 0; i < 8; ++i) {
        u0 += p[i] * vwr[0][i];
        u1 += p[i] * vwr[1][i];
        u2 += p[i] * vwr[2][i];
      }
#pragma unroll
      for (int off = 32; off; off >>= 1) {
        sum += __shfl_xor(sum, off);
        u0  += __shfl_xor(u0, off);
        u1  += __shfl_xor(u1, off);
        u2  += __shfl_xor(u2, off);
      }
      if (lane == 0) {
        const float inv = 1.0f / sum;
        const size_t base = (size_t)b * 3 * 512 + (e0 + el0 + e);
        U[base]        = (_Float16)(u0 * inv);
        U[base + 512]  = (_Float16)(u1 * inv);
        U[base + 1024] = (_Float16)(u2 * inv);
      }
    }
  }
}

// ---------------------------------------------------------------------------
// Stage 3 v6: BK=64 (8 iterations -- halves barrier-latency exposures).
// out[r][t] = sum_e U[r][e]*Wo[t][e] + x[(b*7+o)][t] + w3sum[o]*bo[t]
// M=192, N=16384, K=512. A=U fp16 [64][64] (8KB), B=Wo fp32 [64][64] (16KB);
// 3 bufs = 72KB -> 2 blocks/CU. Counted-vmcnt pipeline as proj.
// ---------------------------------------------------------------------------
__global__ __launch_bounds__(256) void out_gemm(
    const _Float16* __restrict__ U, const float* __restrict__ Wo,
    const float* __restrict__ x, const float* __restrict__ bo,
    const float* __restrict__ W3, float* __restrict__ outY)
{
  __shared__ _Float16 Au[3][64 * 64];  // 8 KB each
  __shared__ float    Bw[3][64 * 64];  // 16 KB each
  const int t = threadIdx.x;
  const int wave = t >> 6, lane = t & 63;
  const int quad = lane >> 4, l16 = lane & 15;
  const int mtile = blockIdx.y, ntile = blockIdx.x;

  float w3s[3];
#pragma unroll
  for (int o = 0; o < 3; ++o) {
    float s = 0.f;
#pragma unroll
    for (int c = 0; c < 16; ++c) s += W3[o * 16 + c];
    w3s[o] = s;
  }

  // A staging: 512 units of 16B (8 halfs), 2 rounds; row = i>>3, u = i&7;
  // src unit = u ^ (row&7)
  const _Float16* aSrc[2];
#pragma unroll
  for (int r = 0; r < 2; ++r) {
    const int i = (r * 4 + wave) * 64 + lane;
    const int row = i >> 3, u = i & 7;
    aSrc[r] = U + (size_t)(mtile * 64 + row) * EE + ((u ^ (row & 7)) << 3);
  }
  // B staging: 1024 units, 4 rounds; row = i>>4, u = i&15; src = u^(row&7)
  const float* bSrc[4];
#pragma unroll
  for (int r = 0; r < 4; ++r) {
    const int i = (r * 4 + wave) * 64 + lane;
    const int row = i >> 4, u = i & 15;
    bSrc[r] = Wo + (size_t)(ntile * 64 + row) * EE + ((u ^ (row & 7)) << 2);
  }

  floatx4 acc[4];
#pragma unroll
  for (int rt = 0; rt < 4; ++rt) acc[rt] = (floatx4){0.f, 0.f, 0.f, 0.f};

  const int brow = wave * 16 + l16;    // this lane's B row (output col)
  const int bsw = brow & 7;

  auto stage = [&](int kt_, int buf_) {        // 6 gloads / thread / tile
    const int ko = kt_ * 64;
#pragma unroll
    for (int r = 0; r < 2; ++r)
      gload_lds16(aSrc[r] + ko, &Au[buf_][(r * 4 + wave) * 512]);
#pragma unroll
    for (int r = 0; r < 4; ++r)
      gload_lds16(bSrc[r] + ko, &Bw[buf_][(r * 4 + wave) * 256]);
  };
  auto compute = [&](int buf_) {
#pragma unroll
    for (int kk = 0; kk < 2; ++kk) {
      float4 b0 = *(const float4*)&Bw[buf_][brow * 64 + (((kk * 8 + quad * 2 + 0) ^ bsw) << 2)];
      float4 b1 = *(const float4*)&Bw[buf_][brow * 64 + (((kk * 8 + quad * 2 + 1) ^ bsw) << 2)];
      const half8 hb = cvt_half8(b0, b1);
      half8 ha[4];
#pragma unroll
      for (int rt = 0; rt < 4; ++rt) {
        const int arow = rt * 16 + l16;
        ha[rt] = *(const half8*)&Au[buf_][arow * 64 + (((kk * 4 + quad) ^ (arow & 7)) << 3)];
      }
      __builtin_amdgcn_s_setprio(1);
#pragma unroll
      for (int rt = 0; rt < 4; ++rt)
        acc[rt] = __builtin_amdgcn_mfma_f32_16x16x32_f16(ha[rt], hb, acc[rt], 0, 0, 0);
      __builtin_amdgcn_s_setprio(0);
    }
  };

  stage(0, 0);
  stage(1, 1);
  asm volatile("s_waitcnt vmcnt(6)" ::: "memory");
  __builtin_amdgcn_s_barrier();
  __builtin_amdgcn_sched_barrier(0);

  int cur = 0;
#pragma unroll
  for (int kt = 0; kt < 6; ++kt) {             // NT=8: mid iters 0..5
    const int nx2 = (cur + 2 >= 3) ? cur - 1 : cur + 2;
    stage(kt + 2, nx2);
    compute(cur);
    asm volatile("s_waitcnt vmcnt(6)" ::: "memory");
    __builtin_amdgcn_s_barrier();
    __builtin_amdgcn_sched_barrier(0);
    cur = (cur + 1 >= 3) ? 0 : cur + 1;
  }
  compute(cur);
  asm volatile("s_waitcnt vmcnt(0)" ::: "memory");
  __builtin_amdgcn_s_barrier();
  __builtin_amdgcn_sched_barrier(0);
  compute((cur + 1 >= 3) ? 0 : cur + 1);

  const int tc = ntile * 64 + wave * 16 + l16;
  const float bot = bo[tc];
#pragma unroll
  for (int rt = 0; rt < 4; ++rt) {
    const int gr = mtile * 64 + rt * 16 + quad * 4;
#pragma unroll
    for (int rg = 0; rg < 4; ++rg) {
      const int rr = gr + rg;
      const int bb = rr / 3, oo = rr - bb * 3;
      const float v = acc[rt][rg]
                    + x[(size_t)(bb * 7 + oo) * TT + tc]
                    + w3s[oo] * bot;
      outY[(size_t)rr * TT + tc] = v;
    }
  }
}

extern "C" void kernel_launch(void* const* d_in, const int* in_sizes, int n_in,
                              void* d_out, int out_size, void* d_ws, size_t ws_size,
                              hipStream_t stream) {
  const float* x  = (const float*)d_in[0];
  const float* W1 = (const float*)d_in[1];
  const float* W2 = (const float*)d_in[2];
  const float* Wq = (const float*)d_in[3];
  const float* bq = (const float*)d_in[4];
  const float* Wk = (const float*)d_in[5];
  const float* bk = (const float*)d_in[6];
  const float* Wv = (const float*)d_in[7];
  const float* bv = (const float*)d_in[8];
  const float* Wo = (const float*)d_in[9];
  const float* bo = (const float*)d_in[10];
  const float* W3 = (const float*)d_in[11];
  float* out = (float*)d_out;

  char* ws = (char*)d_ws;
  float* Xq      = (float*)ws;                  // 192*512  fp32 = 393216 B
  float* Xkv     = (float*)(ws + 393216);       // 256*1024 fp32 = 1048576 B
  _Float16* U    = (_Float16*)(ws + 1441792);   // 192*512  fp16 = 196608 B
  float* P       = (float*)(ws + 1638400);      // CH planes x 360448 fp32

  // pick split-K chunk count by available workspace (CH planes of 1.44 MB)
  int CH = 16;
  while (CH > 2 && ws_size < 1638400ull + (size_t)CH * PSZ * 4) CH >>= 1;
  const int KL = 16384 / CH;                    // K per chunk
  const int NT = KL / 32;                       // k-tiles per block
  const int nblk = 44 * CH;                     // divisible by 8 for all CH
  const int cpx = nblk / 8;

  // merged projections -> partial planes (no atomics, no zeroing needed)
  proj_gemm<<<dim3(nblk), 256, 0, stream>>>(x, Wq, Wk, Wv, P, KL, NT, cpx);
  // sum CH planes -> Xq, Xkv
  reduce_p<<<dim3(352), 256, 0, stream>>>((const floatx4*)P, Xq, Xkv, CH);
  // attention middle -> U (192 x 512 fp16)
  attn_mid<<<dim3(8, BB), 256, 0, stream>>>(Xq, Xkv, W1, W2, W3, bq, bk, bv, U);
  // final projection + residual + bias
  out_gemm<<<dim3(256, 3), 256, 0, stream>>>(U, Wo, x, bo, W3, out);
}

// Round 6
// 283.436 us; speedup vs baseline: 1.0126x; 1.0126x over previous
//
#include <hip/hip_runtime.h>

#define BB 64
#define TT 16384
#define EE 512

// partial-plane: Xq part (192*512) + Xkv part (256*1024) = 360448 floats
#define PSZ 360448
#define PQ_OFF 98304

typedef _Float16 half8 __attribute__((ext_vector_type(8)));
typedef float floatx4 __attribute__((ext_vector_type(4)));

static __device__ __forceinline__ half8 cvt_half8(float4 a, float4 b) {
  half8 h;
  h[0] = (_Float16)a.x; h[1] = (_Float16)a.y; h[2] = (_Float16)a.z; h[3] = (_Float16)a.w;
  h[4] = (_Float16)b.x; h[5] = (_Float16)b.y; h[6] = (_Float16)b.z; h[7] = (_Float16)b.w;
  return h;
}

// ---------------------------------------------------------------------------
// Stage 1 v7: TRAFFIC-MINIMIZED tiles. R5 post-mortem: across R0/R3/R4/R5,
// proj time == staged-read-traffic / ~6-8 TB/s (540MB->90us, 721->90 at
// 8TB/s L2-boosted, 1.5GB->173, 553->93) regardless of sync structure --
// the bottleneck is L2/L3 delivery BW for staging RE-reads, nothing else
// (issue util ~2%, HBM 14%, MFMA 5%). Fix = fewer re-reads:
//   kv tiles 128x256 (A x4, B x2), q tiles 192x256 (M whole: B x1)
//   -> 260 MB total (was 553). fp16 LDS via register staging (T14
//   async-split: loads -> compute(cur) -> cvt+ds_write(nxt) -> ONE barrier)
//   so double-buffered big tiles fit: A 12KB + B 16KB per buf = 56KB.
//   XOR unit swizzle u^=(row^(row>>2))&3 -> max 2-way bank aliasing (free).
//   10 tiles x CH chunks; per-XCD chunk slice ~4MB == one L2 (R4 evidence:
//   chunk-fits-L2 lifts effective staging BW to ~8 TB/s).
// Split-K partials to distinct planes (R5, no atomics) + reduce_p.
// ---------------------------------------------------------------------------
__global__ __launch_bounds__(512) void proj_gemm(
    const float* __restrict__ x, const float* __restrict__ Wq,
    const float* __restrict__ Wk, const float* __restrict__ Wv,
    float* __restrict__ P, int KL, int NT, int cpx)
{
  __shared__ _Float16 Ah[2][192 * 32];   // 12 KB each
  __shared__ _Float16 Bh[2][256 * 32];   // 16 KB each  -> 56 KB total
  const int t = threadIdx.x;
  const int wave = t >> 6, lane = t & 63;
  const int quad = lane >> 4, l16 = lane & 15;
  const int wr = wave >> 2, wc = wave & 3;       // 2 x 4 wave grid

  const int orig = blockIdx.x;
  const int logical = (orig & 7) * cpx + (orig >> 3);
  const int chunk = logical / 10;
  const int tile  = logical - chunk * 10;
  const int k0 = chunk * KL;

  const bool isQ = (tile < 2);
  int ntile, mtile, MR, WM, BM, pbase, ldout;
  const float* Wsrc;
  if (isQ) {                                     // Xq: 192 x 256, 2 ntiles
    ntile = tile; mtile = 0;
    Wsrc = Wq + (size_t)(ntile * 256) * TT;
    MR = 6; WM = 96; BM = 192; pbase = 0; ldout = 512;
  } else {                                       // Xkv: 2m x 4n of 128x256
    const int t2 = tile - 2;
    mtile = t2 >> 2; ntile = t2 & 3;
    Wsrc = (ntile < 2) ? (Wk + (size_t)(ntile * 256) * TT)
                       : (Wv + (size_t)((ntile - 2) * 256) * TT);
    MR = 4; WM = 64; BM = 128; pbase = PQ_OFF; ldout = 1024;
  }

  // ---- staging assignments (granule = 16 consecutive floats = 64B) ----
  // A: 2*BM granules, thread t < 2*BM: row = t>>1, half h = t&1
  const bool aAct = (t < 2 * BM);
  const int arow_s = t >> 1, ah = t & 1;
  const float* aSrc = x;
  if (aAct) {
    const int rg_ = (isQ ? 0 : mtile * 128) + arow_s;
    int b_, j_;
    if (isQ) { b_ = (rg_ * 21846) >> 16; j_ = rg_ - b_ * 3; }   // rg_/3
    else     { b_ = rg_ >> 2; j_ = (rg_ & 3) + 3; }
    aSrc = x + (size_t)(b_ * 7 + j_) * TT + k0 + ah * 16;
  }
  // B: 512 granules (256 rows x 2), all threads
  const int brow_s = t >> 1, bh = t & 1;
  const float* bSrc = Wsrc + (size_t)brow_s * TT + k0 + bh * 16;

  // LDS write offsets (unit swizzle: u' = u ^ ((row ^ (row>>2)) & 3))
  const int aswr = (arow_s ^ (arow_s >> 2)) & 3;
  const int bswr = (brow_s ^ (brow_s >> 2)) & 3;
  const int aoff0 = arow_s * 32 + ((((ah << 1) | 0) ^ aswr) << 3);
  const int aoff1 = arow_s * 32 + ((((ah << 1) | 1) ^ aswr) << 3);
  const int boff0 = brow_s * 32 + ((((bh << 1) | 0) ^ bswr) << 3);
  const int boff1 = brow_s * 32 + ((((bh << 1) | 1) ^ bswr) << 3);

  floatx4 acc[6][4];
#pragma unroll
  for (int mr = 0; mr < 6; ++mr)
#pragma unroll
    for (int ct = 0; ct < 4; ++ct)
      acc[mr][ct] = (floatx4){0.f, 0.f, 0.f, 0.f};

  float4 la0, la1, la2, la3, lb0, lb1, lb2, lb3;

  auto stage_load = [&](int kt_) {               // issue 8 coalesced loads
    const float* ap = aSrc + kt_ * 32;
    const float* bp = bSrc + kt_ * 32;
    if (aAct) {
      la0 = *(const float4*)(ap);
      la1 = *(const float4*)(ap + 4);
      la2 = *(const float4*)(ap + 8);
      la3 = *(const float4*)(ap + 12);
    }
    lb0 = *(const float4*)(bp);
    lb1 = *(const float4*)(bp + 4);
    lb2 = *(const float4*)(bp + 8);
    lb3 = *(const float4*)(bp + 12);
  };
  auto stage_write = [&](int buf_) {             // cvt fp32->fp16, ds_write
    if (aAct) {
      *(half8*)&Ah[buf_][aoff0] = cvt_half8(la0, la1);
      *(half8*)&Ah[buf_][aoff1] = cvt_half8(la2, la3);
    }
    *(half8*)&Bh[buf_][boff0] = cvt_half8(lb0, lb1);
    *(half8*)&Bh[buf_][boff1] = cvt_half8(lb2, lb3);
  };
  auto compute = [&](int buf_) {
    half8 hb[4];
#pragma unroll
    for (int ct = 0; ct < 4; ++ct) {
      const int br = wc * 64 + ct * 16 + l16;
      const int sb = (br ^ (br >> 2)) & 3;
      hb[ct] = *(const half8*)&Bh[buf_][br * 32 + ((quad ^ sb) << 3)];
    }
#pragma unroll
    for (int mr = 0; mr < 6; ++mr) {
      if (mr < MR) {                             // uniform guard, static idx
        const int ar = wr * WM + mr * 16 + l16;
        const int sa = (ar ^ (ar >> 2)) & 3;
        const half8 ha = *(const half8*)&Ah[buf_][ar * 32 + ((quad ^ sa) << 3)];
#pragma unroll
        for (int ct = 0; ct < 4; ++ct)
          acc[mr][ct] = __builtin_amdgcn_mfma_f32_16x16x32_f16(ha, hb[ct], acc[mr][ct], 0, 0, 0);
      }
    }
  };

  stage_load(0);
  stage_write(0);
  __syncthreads();
  int cur = 0;
  for (int kt = 0; kt < NT; ++kt) {
    if (kt + 1 < NT) stage_load(kt + 1);         // loads fly under compute
    compute(cur);
    if (kt + 1 < NT) {
      stage_write(cur ^ 1);                      // write OTHER buffer: safe
      __syncthreads();                           // one barrier per k-tile
      cur ^= 1;
    }
  }

  // epilogue: plain stores into this chunk's plane (C/D: col=l16, row=quad*4+rg)
  float* outP = P + (size_t)chunk * PSZ + pbase;
#pragma unroll
  for (int mr = 0; mr < 6; ++mr) {
    if (mr < MR) {
#pragma unroll
      for (int ct = 0; ct < 4; ++ct) {
        const int gr = (isQ ? 0 : mtile * 128) + wr * WM + mr * 16 + quad * 4;
        const int gc = ntile * 256 + wc * 64 + ct * 16 + l16;
#pragma unroll
        for (int rg = 0; rg < 4; ++rg)
          outP[(size_t)(gr + rg) * ldout + gc] = acc[mr][ct][rg];
      }
    }
  }
}

// ---------------------------------------------------------------------------
// Reduce CH partial planes -> Xq / Xkv. 352 blocks x 256 thr x 1 float4.
// ---------------------------------------------------------------------------
__global__ __launch_bounds__(256) void reduce_p(
    const floatx4* __restrict__ P4, float* __restrict__ Xq,
    float* __restrict__ Xkv, int CH)
{
  const int i = blockIdx.x * 256 + threadIdx.x;   // 0..90111
  floatx4 s = P4[i];
  for (int c = 1; c < CH; ++c) s += P4[(size_t)c * (PSZ / 4) + i];
  if (i < PQ_OFF / 4) ((floatx4*)Xq)[i] = s;
  else                ((floatx4*)Xkv)[i - PQ_OFF / 4] = s;
}

// ---------------------------------------------------------------------------
// Stage 2: per (batch, 64-wide e-chunk): build K(16x512), VW(3x512), Q(16x64)
// in LDS, then per e-row: S = 0.25*Q^T K, softmax over f, u[o,e]=P·VW[o]/den.
// (unchanged -- verified correct)
// ---------------------------------------------------------------------------
__global__ __launch_bounds__(256) void attn_mid(
    const float* __restrict__ Xq, const float* __restrict__ Xkv,
    const float* __restrict__ W1, const float* __restrict__ W2,
    const float* __restrict__ W3,
    const float* __restrict__ bq, const float* __restrict__ bk,
    const float* __restrict__ bv, _Float16* __restrict__ U)
{
  __shared__ float Ks[16][512];
  __shared__ float VW[3][512];
  __shared__ float Qs[16][64];
  __shared__ float Xs[4][512];
  __shared__ float W1s[48], W2s[64], W3s[48], W32s[12], w3sum[3];
  const int t = threadIdx.x;
  const int b = blockIdx.y;
  const int e0 = blockIdx.x * 64;

  if (t < 48) W1s[t] = W1[t];
  if (t >= 64 && t < 128) W2s[t - 64] = W2[t - 64];
  if (t >= 128 && t < 176) W3s[t - 128] = W3[t - 128];
  __syncthreads();
  if (t < 12) {                       // W32[o][j] = sum_c W3[o][c]*W2[c][j]
    const int o = t >> 2, jj = t & 3;
    float s = 0.f;
    for (int c = 0; c < 16; ++c) s += W3s[o * 16 + c] * W2s[c * 4 + jj];
    W32s[t] = s;
  }
  if (t >= 16 && t < 19) {
    const int o = t - 16;
    float s = 0.f;
    for (int c = 0; c < 16; ++c) s += W3s[o * 16 + c];
    w3sum[o] = s;
  }
  // stage Xk, build K
  for (int i = t; i < 2048; i += 256) {
    const int jj = i >> 9, f = i & 511;
    Xs[jj][f] = Xkv[(size_t)(b * 4 + jj) * 1024 + f];
  }
  __syncthreads();
  for (int i = t; i < 8192; i += 256) {
    const int c = i >> 9, f = i & 511;
    float s = bk[f];
#pragma unroll
    for (int jj = 0; jj < 4; ++jj) s += W2s[c * 4 + jj] * Xs[jj][f];
    Ks[c][f] = s;
  }
  __syncthreads();
  // stage Xv, build VW
  for (int i = t; i < 2048; i += 256) {
    const int jj = i >> 9, f = i & 511;
    Xs[jj][f] = Xkv[(size_t)(b * 4 + jj) * 1024 + 512 + f];
  }
  __syncthreads();
  for (int i = t; i < 1536; i += 256) {
    const int o = i >> 9, f = i & 511;
    float s = w3sum[o] * bv[f];
#pragma unroll
    for (int jj = 0; jj < 4; ++jj) s += W32s[o * 4 + jj] * Xs[jj][f];
    VW[o][f] = s;
  }
  // build Q for this e-chunk
  for (int i = t; i < 1024; i += 256) {
    const int c = i >> 6, el = i & 63;
    float s = bq[e0 + el];
#pragma unroll
    for (int jj = 0; jj < 3; ++jj)
      s += W1s[c * 3 + jj] * Xq[(size_t)(b * 3 + jj) * 512 + e0 + el];
    Qs[c][el] = s;
  }
  __syncthreads();

  const int wave = t >> 6, lane = t & 63;
  float vwr[3][8];
#pragma unroll
  for (int o = 0; o < 3; ++o) {
    float4 va = *(const float4*)&VW[o][lane * 8];
    float4 vb = *(const float4*)&VW[o][lane * 8 + 4];
    vwr[o][0] = va.x; vwr[o][1] = va.y; vwr[o][2] = va.z; vwr[o][3] = va.w;
    vwr[o][4] = vb.x; vwr[o][5] = vb.y; vwr[o][6] = vb.z; vwr[o][7] = vb.w;
  }

  for (int g = 0; g < 4; ++g) {       // 4 groups of 4 e-rows per wave
    const int el0 = wave * 16 + g * 4;
    float s[4][8];
#pragma unroll
    for (int e = 0; e < 4; ++e)
#pragma unroll
      for (int i = 0; i < 8; ++i) s[e][i] = 0.f;
#pragma unroll
    for (int c = 0; c < 16; ++c) {
      float4 k0 = *(const float4*)&Ks[c][lane * 8];
      float4 k1 = *(const float4*)&Ks[c][lane * 8 + 4];
      float4 qv = *(const float4*)&Qs[c][el0];
      float qa[4] = {qv.x, qv.y, qv.z, qv.w};
#pragma unroll
      for (int e = 0; e < 4; ++e) {
        const float q = qa[e];
        s[e][0] += q * k0.x; s[e][1] += q * k0.y; s[e][2] += q * k0.z; s[e][3] += q * k0.w;
        s[e][4] += q * k1.x; s[e][5] += q * k1.y; s[e][6] += q * k1.z; s[e][7] += q * k1.w;
      }
    }
#pragma unroll
    for (int e = 0; e < 4; ++e) {
      float mx = s[e][0];
#pragma unroll
      for (int i = 1; i < 8; ++i) mx = fmaxf(mx, s[e][i]);
#pragma unroll
      for (int off = 32; off; off >>= 1) mx = fmaxf(mx, __shfl_xor(mx, off));
      float p[8], sum = 0.f;
#pragma unroll
      for (int i = 0; i < 8; ++i) { p[i] = __expf(0.25f * (s[e][i] - mx)); sum += p[i]; }
      float u0 = 0.f, u1 = 0.f, u2 = 0.f;
#pragma unroll
      for (int i = 0; i < 8; ++i) {
        u0 += p[i] * vwr[0][i];
        u1 += p[i] * vwr[1][i];
        u2 += p[i] * vwr[2][i];
      }
#pragma unroll
      for (int off = 32; off; off >>= 1) {
        sum += __shfl_xor(sum, off);
        u0  += __shfl_xor(u0, off);
        u1  += __shfl_xor(u1, off);
        u2  += __shfl_xor(u2, off);
      }
      if (lane == 0) {
        const float inv = 1.0f / sum;
        const size_t base = (size_t)b * 3 * 512 + (e0 + el0 + e);
        U[base]        = (_Float16)(u0 * inv);
        U[base + 512]  = (_Float16)(u1 * inv);
        U[base + 1024] = (_Float16)(u2 * inv);
      }
    }
  }
}

// ---------------------------------------------------------------------------
// Stage 3 v7: traffic-minimized. BM=192 (ALL M: Wo read exactly once),
// BN=64 -> traffic 110 MB (was ~175). A=U fp16 copied to LDS; B=Wo cvt fp16.
// 2x(12+4)KB = 32KB LDS -> 5 blocks/CU; 256 blocks x 256 thr.
// Same one-barrier reg-staged double-buffer as proj.
// ---------------------------------------------------------------------------
__global__ __launch_bounds__(256) void out_gemm(
    const _Float16* __restrict__ U, const float* __restrict__ Wo,
    const float* __restrict__ x, const float* __restrict__ bo,
    const float* __restrict__ W3, float* __restrict__ outY)
{
  __shared__ _Float16 Au[2][192 * 32];  // 12 KB each
  __shared__ _Float16 Bw[2][64 * 32];   //  4 KB each
  const int t = threadIdx.x;
  const int wave = t >> 6, lane = t & 63;
  const int quad = lane >> 4, l16 = lane & 15;
  const int wr = wave >> 1, wc = wave & 1;       // 2 x 2 wave grid
  const int ntile = blockIdx.x;

  float w3s[3];
#pragma unroll
  for (int o = 0; o < 3; ++o) {
    float s = 0.f;
#pragma unroll
    for (int c = 0; c < 16; ++c) s += W3[o * 16 + c];
    w3s[o] = s;
  }

  // A: 768 16B-units (192 rows x 4); thread handles units t, t+256, t+512
  const _Float16* auSrc[3];
  int auoff[3];
#pragma unroll
  for (int r = 0; r < 3; ++r) {
    const int un = t + r * 256;
    const int row = un >> 2, u = un & 3;
    const int sw = (row ^ (row >> 2)) & 3;
    auSrc[r] = U + (size_t)row * EE + u * 8;
    auoff[r] = row * 32 + ((u ^ sw) << 3);
  }
  // B: 128 granules (64 rows x 2), threads t<128
  const bool bAct = (t < 128);
  const int brow_s = t >> 1, bh = t & 1;
  const float* bSrc = Wo + (size_t)(ntile * 64 + brow_s) * EE + bh * 16;
  const int bswr = (brow_s ^ (brow_s >> 2)) & 3;
  const int boff0 = brow_s * 32 + ((((bh << 1) | 0) ^ bswr) << 3);
  const int boff1 = brow_s * 32 + ((((bh << 1) | 1) ^ bswr) << 3);

  floatx4 acc[6][2];
#pragma unroll
  for (int mr = 0; mr < 6; ++mr)
#pragma unroll
    for (int ct = 0; ct < 2; ++ct)
      acc[mr][ct] = (floatx4){0.f, 0.f, 0.f, 0.f};

  half8 lau0, lau1, lau2;
  float4 lb0, lb1, lb2, lb3;

  auto stage_load = [&](int kt_) {
    lau0 = *(const half8*)(auSrc[0] + kt_ * 32);
    lau1 = *(const half8*)(auSrc[1] + kt_ * 32);
    lau2 = *(const half8*)(auSrc[2] + kt_ * 32);
    if (bAct) {
      const float* bp = bSrc + kt_ * 32;
      lb0 = *(const float4*)(bp);
      lb1 = *(const float4*)(bp + 4);
      lb2 = *(const float4*)(bp + 8);
      lb3 = *(const float4*)(bp + 12);
    }
  };
  auto stage_write = [&](int buf_) {
    *(half8*)&Au[buf_][auoff[0]] = lau0;
    *(half8*)&Au[buf_][auoff[1]] = lau1;
    *(half8*)&Au[buf_][auoff[2]] = lau2;
    if (bAct) {
      *(half8*)&Bw[buf_][boff0] = cvt_half8(lb0, lb1);
      *(half8*)&Bw[buf_][boff1] = cvt_half8(lb2, lb3);
    }
  };
  auto compute = [&](int buf_) {
    half8 hb[2];
#pragma unroll
    for (int ct = 0; ct < 2; ++ct) {
      const int br = wc * 32 + ct * 16 + l16;
      const int sb = (br ^ (br >> 2)) & 3;
      hb[ct] = *(const half8*)&Bw[buf_][br * 32 + ((quad ^ sb) << 3)];
    }
#pragma unroll
    for (int mr = 0; mr < 6; ++mr) {
      const int ar = wr * 96 + mr * 16 + l16;
      const int sa = (ar ^ (ar >> 2)) & 3;
      const half8 ha = *(const half8*)&Au[buf_][ar * 32 + ((quad ^ sa) << 3)];
#pragma unroll
      for (int ct = 0; ct < 2; ++ct)
        acc[mr][ct] = __builtin_amdgcn_mfma_f32_16x16x32_f16(ha, hb[ct], acc[mr][ct], 0, 0, 0);
    }
  };

  stage_load(0);
  stage_write(0);
  __syncthreads();
  int cur = 0;
  for (int kt = 0; kt < 16; ++kt) {
    if (kt + 1 < 16) stage_load(kt + 1);
    compute(cur);
    if (kt + 1 < 16) {
      stage_write(cur ^ 1);
      __syncthreads();
      cur ^= 1;
    }
  }

#pragma unroll
  for (int mr = 0; mr < 6; ++mr) {
#pragma unroll
    for (int ct = 0; ct < 2; ++ct) {
      const int tc = ntile * 64 + wc * 32 + ct * 16 + l16;
      const float bot = bo[tc];
#pragma unroll
      for (int rg = 0; rg < 4; ++rg) {
        const int rr = wr * 96 + mr * 16 + quad * 4 + rg;
        const int bb = rr / 3, oo = rr - bb * 3;
        const float v = acc[mr][ct][rg]
                      + x[(size_t)(bb * 7 + oo) * TT + tc]
                      + w3s[oo] * bot;
        outY[(size_t)rr * TT + tc] = v;
      }
    }
  }
}

extern "C" void kernel_launch(void* const* d_in, const int* in_sizes, int n_in,
                              void* d_out, int out_size, void* d_ws, size_t ws_size,
                              hipStream_t stream) {
  const float* x  = (const float*)d_in[0];
  const float* W1 = (const float*)d_in[1];
  const float* W2 = (const float*)d_in[2];
  const float* Wq = (const float*)d_in[3];
  const float* bq = (const float*)d_in[4];
  const float* Wk = (const float*)d_in[5];
  const float* bk = (const float*)d_in[6];
  const float* Wv = (const float*)d_in[7];
  const float* bv = (const float*)d_in[8];
  const float* Wo = (const float*)d_in[9];
  const float* bo = (const float*)d_in[10];
  const float* W3 = (const float*)d_in[11];
  float* out = (float*)d_out;

  char* ws = (char*)d_ws;
  float* Xq      = (float*)ws;                  // 192*512  fp32 = 393216 B
  float* Xkv     = (float*)(ws + 393216);       // 256*1024 fp32 = 1048576 B
  _Float16* U    = (_Float16*)(ws + 1441792);   // 192*512  fp16 = 196608 B
  float* P       = (float*)(ws + 1638400);      // CH planes x 360448 fp32

  // pick split-K chunk count by available workspace (CH planes of 1.44 MB)
  int CH = 32;
  while (CH > 4 && ws_size < 1638400ull + (size_t)CH * PSZ * 4) CH >>= 1;
  const int KL = 16384 / CH;                    // K per chunk
  const int NT = KL / 32;                       // k-tiles per block
  const int nblk = 10 * CH;                     // divisible by 8 for all CH
  const int cpx = nblk / 8;

  // merged projections -> partial planes (no atomics)
  proj_gemm<<<dim3(nblk), 512, 0, stream>>>(x, Wq, Wk, Wv, P, KL, NT, cpx);
  // sum CH planes -> Xq, Xkv
  reduce_p<<<dim3(352), 256, 0, stream>>>((const floatx4*)P, Xq, Xkv, CH);
  // attention middle -> U (192 x 512 fp16)
  attn_mid<<<dim3(8, BB), 256, 0, stream>>>(Xq, Xkv, W1, W2, W3, bq, bk, bv, U);
  // final projection + residual + bias
  out_gemm<<<dim3(256), 256, 0, stream>>>(U, Wo, x, bo, W3, out);
}

// Round 8
// 259.835 us; speedup vs baseline: 1.1046x; 1.0908x over previous
//
#include <hip/hip_runtime.h>

#define BB 64
#define TT 16384
#define EE 512

// partial-plane: Xq part (192*512) + Xkv part (256*1024) = 360448 elements
#define PSZ 360448
#define PQ_OFF 98304

typedef _Float16 half8 __attribute__((ext_vector_type(8)));
typedef float floatx4 __attribute__((ext_vector_type(4)));

static __device__ __forceinline__ half8 cvt_half8(float4 a, float4 b) {
  half8 h;
  h[0] = (_Float16)a.x; h[1] = (_Float16)a.y; h[2] = (_Float16)a.z; h[3] = (_Float16)a.w;
  h[4] = (_Float16)b.x; h[5] = (_Float16)b.y; h[6] = (_Float16)b.z; h[7] = (_Float16)b.w;
  return h;
}

static __device__ __forceinline__ void gload_lds16(const void* g, void* l) {
  __builtin_amdgcn_global_load_lds(
      (const __attribute__((address_space(1))) void*)g,
      (__attribute__((address_space(3))) void*)l, 16, 0, 0);
}

// ---------------------------------------------------------------------------
// Stage 1 v8 (R8 = byte-identical resubmit of R7; container failed twice with
// no diagnostics -- R2 had the same signature and the identical source passed
// at R3. Full fault audit found no OOB/deadlock/limit violation; 128KB static
// LDS is the m201-verified configuration).
// Design: min-traffic mega-tiles x max-delivery staging.
//  - KV tile 256x256 (FULL M -> Wk/Wv read exactly once), Q tile 192x256
//    -> staged total 193 MB (W 100 read once + X 92).
//  - 1024 threads (16 waves = 4/SIMD from ONE block -> full CU concurrency),
//    fp32 LDS 2x(32+32) KB = 128 KB static, gload_lds staging,
//    raw s_barrier + counted vmcnt(4), sched_barrier fences.
//  - A-row clamp makes all waves issue exactly 4 loads/tile -> uniform vmcnt.
//  - 6 tiles x CH=32 chunks = 192 blocks; XCD-affinity map keeps each XCD on
//    whole chunks.
//  - fp16 partial planes (sigma~0.18 >> fp16 eps; tol 0.03) -> WRITE 45->23MB.
// tiles 0,1: Q (192 x 256); tiles 2..5: KV (256 x 256), <2 -> Wk else Wv.
// ---------------------------------------------------------------------------
__global__ __launch_bounds__(1024) void proj_gemm(
    const float* __restrict__ x, const float* __restrict__ Wq,
    const float* __restrict__ Wk, const float* __restrict__ Wv,
    _Float16* __restrict__ P, int KL, int NT, int cpx)
{
  __shared__ float Abuf[2][256 * 32];   // 32 KB each
  __shared__ float Bbuf[2][256 * 32];   // 32 KB each  -> 128 KB total
  const int t = threadIdx.x;
  const int wave = t >> 6, lane = t & 63;
  const int quad = lane >> 4, l16 = lane & 15;
  const int wr = wave >> 2, wc = wave & 3;       // 4 x 4 wave grid

  const int orig = blockIdx.x;
  const int logical = (orig & 7) * cpx + (orig >> 3);
  const int chunk = logical / 6;
  const int tile  = logical - chunk * 6;
  const int k0 = chunk * KL;

  const bool isQ = (tile < 2);
  int ntile, MR, WM, BM, pbase, ldout;
  const float* Wsrc;
  if (isQ) {                                     // Q: 192 x 256
    ntile = tile;
    Wsrc = Wq + (size_t)(ntile * 256) * TT;
    MR = 3; WM = 48; BM = 192; pbase = 0; ldout = 512;
  } else {                                       // KV: 256 x 256
    ntile = tile - 2;
    Wsrc = (ntile < 2) ? (Wk + (size_t)(ntile * 256) * TT)
                       : (Wv + (size_t)((ntile - 2) * 256) * TT);
    MR = 4; WM = 64; BM = 256; pbase = PQ_OFF; ldout = 1024;
  }

  // staging: A/B each 2048 16B-units (256 rows x 8), 2 rounds x 1024 threads.
  // round r: unit i = r*1024 + t; row = i>>3; u = i&7; src unit = u^(row&7)
  // (swizzle source-side, LDS linear). Q A-rows >= BM clamp to row 0 (dup
  // load into unread LDS) so EVERY wave issues exactly 4 gloads/tile.
  const float* aSrc[2];
  const float* bSrc[2];
#pragma unroll
  for (int r = 0; r < 2; ++r) {
    const int i = r * 1024 + t;
    const int row0 = i >> 3, u = i & 7;
    const int row = (row0 < BM) ? row0 : 0;      // clamp (Q only)
    int b_, j_;
    if (isQ) { b_ = (row * 21846) >> 16; j_ = row - b_ * 3; }
    else     { b_ = row >> 2; j_ = (row & 3) + 3; }
    aSrc[r] = x + (size_t)(b_ * 7 + j_) * TT + k0 + ((u ^ (row & 7)) << 2);
    const int brow = i >> 3, bu = i & 7;
    bSrc[r] = Wsrc + (size_t)brow * TT + k0 + ((bu ^ (brow & 7)) << 2);
  }

  floatx4 acc[4][4];
#pragma unroll
  for (int mr = 0; mr < 4; ++mr)
#pragma unroll
    for (int ct = 0; ct < 4; ++ct)
      acc[mr][ct] = (floatx4){0.f, 0.f, 0.f, 0.f};

  auto stage = [&](int kt_, int buf_) {          // exactly 4 gloads / thread
    const int ko = kt_ * 32;
#pragma unroll
    for (int r = 0; r < 2; ++r) {
      gload_lds16(aSrc[r] + ko, &Abuf[buf_][r * 4096 + wave * 256]);
      gload_lds16(bSrc[r] + ko, &Bbuf[buf_][r * 4096 + wave * 256]);
    }
  };
  auto compute = [&](int buf_) {
    half8 hb[4];
#pragma unroll
    for (int ct = 0; ct < 4; ++ct) {
      const int br = wc * 64 + ct * 16 + l16;
      const int sb = br & 7;
      float4 b0 = *(const float4*)&Bbuf[buf_][br * 32 + ((((quad << 1) | 0) ^ sb) << 2)];
      float4 b1 = *(const float4*)&Bbuf[buf_][br * 32 + ((((quad << 1) | 1) ^ sb) << 2)];
      hb[ct] = cvt_half8(b0, b1);
    }
#pragma unroll
    for (int mr = 0; mr < 4; ++mr) {
      if (mr < MR) {                             // block-uniform guard
        const int ar = wr * WM + mr * 16 + l16;
        const int sa = ar & 7;
        float4 a0 = *(const float4*)&Abuf[buf_][ar * 32 + ((((quad << 1) | 0) ^ sa) << 2)];
        float4 a1 = *(const float4*)&Abuf[buf_][ar * 32 + ((((quad << 1) | 1) ^ sa) << 2)];
        const half8 ha = cvt_half8(a0, a1);
        __builtin_amdgcn_s_setprio(1);
#pragma unroll
        for (int ct = 0; ct < 4; ++ct)
          acc[mr][ct] = __builtin_amdgcn_mfma_f32_16x16x32_f16(ha, hb[ct], acc[mr][ct], 0, 0, 0);
        __builtin_amdgcn_s_setprio(0);
      }
    }
  };

  // prologue: 2 tiles issued; wait only the oldest (4 of 8 outstanding)
  stage(0, 0);
  stage(1, 1);
  asm volatile("s_waitcnt vmcnt(4)" ::: "memory");
  __builtin_amdgcn_s_barrier();
  __builtin_amdgcn_sched_barrier(0);

  int cur = 0;
  for (int kt = 0; kt < NT; ++kt) {
    compute(cur);
    __builtin_amdgcn_s_barrier();                // all waves done reading cur
    if (kt + 2 < NT) {
      stage(kt + 2, cur);                        // refill cur with tile kt+2
      asm volatile("s_waitcnt vmcnt(4)" ::: "memory");   // kt+1 resident
    } else {
      asm volatile("s_waitcnt vmcnt(0)" ::: "memory");   // tail drain
    }
    __builtin_amdgcn_s_barrier();
    __builtin_amdgcn_sched_barrier(0);
    cur ^= 1;
  }

  // epilogue: fp16 stores into this chunk's plane (C/D: col=l16, row=quad*4+rg)
  _Float16* outP = P + (size_t)chunk * PSZ + pbase;
#pragma unroll
  for (int mr = 0; mr < 4; ++mr) {
    if (mr < MR) {
#pragma unroll
      for (int ct = 0; ct < 4; ++ct) {
        const int gr = wr * WM + mr * 16 + quad * 4;
        const int gc = ntile * 256 + wc * 64 + ct * 16 + l16;
#pragma unroll
        for (int rg = 0; rg < 4; ++rg)
          outP[(size_t)(gr + rg) * ldout + gc] = (_Float16)acc[mr][ct][rg];
      }
    }
  }
}

// ---------------------------------------------------------------------------
// Reduce CH fp16 partial planes -> fp32 Xq / Xkv. 176 blocks x 256 thr x
// 8 halfs = 360448 elements, exactly one plane.
// ---------------------------------------------------------------------------
__global__ __launch_bounds__(256) void reduce_p(
    const _Float16* __restrict__ P, float* __restrict__ Xq,
    float* __restrict__ Xkv, int CH)
{
  const int i = blockIdx.x * 256 + threadIdx.x;   // 0..45055
  float s[8] = {0.f, 0.f, 0.f, 0.f, 0.f, 0.f, 0.f, 0.f};
  for (int c = 0; c < CH; ++c) {
    const half8 v = *(const half8*)(P + (size_t)c * PSZ + (size_t)i * 8);
#pragma unroll
    for (int k = 0; k < 8; ++k) s[k] += (float)v[k];
  }
  const float4 lo = {s[0], s[1], s[2], s[3]};
  const float4 hi = {s[4], s[5], s[6], s[7]};
  if (i < PQ_OFF / 8) {
    ((float4*)Xq)[i * 2]     = lo;
    ((float4*)Xq)[i * 2 + 1] = hi;
  } else {
    const int j = i - PQ_OFF / 8;
    ((float4*)Xkv)[j * 2]     = lo;
    ((float4*)Xkv)[j * 2 + 1] = hi;
  }
}

// ---------------------------------------------------------------------------
// Stage 2: per (batch, 64-wide e-chunk): build K(16x512), VW(3x512), Q(16x64)
// in LDS, then per e-row: S = 0.25*Q^T K, softmax over f, u[o,e]=P·VW[o]/den.
// (unchanged -- verified correct)
// ---------------------------------------------------------------------------
__global__ __launch_bounds__(256) void attn_mid(
    const float* __restrict__ Xq, const float* __restrict__ Xkv,
    const float* __restrict__ W1, const float* __restrict__ W2,
    const float* __restrict__ W3,
    const float* __restrict__ bq, const float* __restrict__ bk,
    const float* __restrict__ bv, _Float16* __restrict__ U)
{
  __shared__ float Ks[16][512];
  __shared__ float VW[3][512];
  __shared__ float Qs[16][64];
  __shared__ float Xs[4][512];
  __shared__ float W1s[48], W2s[64], W3s[48], W32s[12], w3sum[3];
  const int t = threadIdx.x;
  const int b = blockIdx.y;
  const int e0 = blockIdx.x * 64;

  if (t < 48) W1s[t] = W1[t];
  if (t >= 64 && t < 128) W2s[t - 64] = W2[t - 64];
  if (t >= 128 && t < 176) W3s[t - 128] = W3[t - 128];
  __syncthreads();
  if (t < 12) {                       // W32[o][j] = sum_c W3[o][c]*W2[c][j]
    const int o = t >> 2, jj = t & 3;
    float s = 0.f;
    for (int c = 0; c < 16; ++c) s += W3s[o * 16 + c] * W2s[c * 4 + jj];
    W32s[t] = s;
  }
  if (t >= 16 && t < 19) {
    const int o = t - 16;
    float s = 0.f;
    for (int c = 0; c < 16; ++c) s += W3s[o * 16 + c];
    w3sum[o] = s;
  }
  // stage Xk, build K
  for (int i = t; i < 2048; i += 256) {
    const int jj = i >> 9, f = i & 511;
    Xs[jj][f] = Xkv[(size_t)(b * 4 + jj) * 1024 + f];
  }
  __syncthreads();
  for (int i = t; i < 8192; i += 256) {
    const int c = i >> 9, f = i & 511;
    float s = bk[f];
#pragma unroll
    for (int jj = 0; jj < 4; ++jj) s += W2s[c * 4 + jj] * Xs[jj][f];
    Ks[c][f] = s;
  }
  __syncthreads();
  // stage Xv, build VW
  for (int i = t; i < 2048; i += 256) {
    const int jj = i >> 9, f = i & 511;
    Xs[jj][f] = Xkv[(size_t)(b * 4 + jj) * 1024 + 512 + f];
  }
  __syncthreads();
  for (int i = t; i < 1536; i += 256) {
    const int o = i >> 9, f = i & 511;
    float s = w3sum[o] * bv[f];
#pragma unroll
    for (int jj = 0; jj < 4; ++jj) s += W32s[o * 4 + jj] * Xs[jj][f];
    VW[o][f] = s;
  }
  // build Q for this e-chunk
  for (int i = t; i < 1024; i += 256) {
    const int c = i >> 6, el = i & 63;
    float s = bq[e0 + el];
#pragma unroll
    for (int jj = 0; jj < 3; ++jj)
      s += W1s[c * 3 + jj] * Xq[(size_t)(b * 3 + jj) * 512 + e0 + el];
    Qs[c][el] = s;
  }
  __syncthreads();

  const int wave = t >> 6, lane = t & 63;
  float vwr[3][8];
#pragma unroll
  for (int o = 0; o < 3; ++o) {
    float4 va = *(const float4*)&VW[o][lane * 8];
    float4 vb = *(const float4*)&VW[o][lane * 8 + 4];
    vwr[o][0] = va.x; vwr[o][1] = va.y; vwr[o][2] = va.z; vwr[o][3] = va.w;
    vwr[o][4] = vb.x; vwr[o][5] = vb.y; vwr[o][6] = vb.z; vwr[o][7] = vb.w;
  }

  for (int g = 0; g < 4; ++g) {       // 4 groups of 4 e-rows per wave
    const int el0 = wave * 16 + g * 4;
    float s[4][8];
#pragma unroll
    for (int e = 0; e < 4; ++e)
#pragma unroll
      for (int i = 0; i < 8; ++i) s[e][i] = 0.f;
#pragma unroll
    for (int c = 0; c < 16; ++c) {
      float4 k0 = *(const float4*)&Ks[c][lane * 8];
      float4 k1 = *(const float4*)&Ks[c][lane * 8 + 4];
      float4 qv = *(const float4*)&Qs[c][el0];
      float qa[4] = {qv.x, qv.y, qv.z, qv.w};
#pragma unroll
      for (int e = 0; e < 4; ++e) {
        const float q = qa[e];
        s[e][0] += q * k0.x; s[e][1] += q * k0.y; s[e][2] += q * k0.z; s[e][3] += q * k0.w;
        s[e][4] += q * k1.x; s[e][5] += q * k1.y; s[e][6] += q * k1.z; s[e][7] += q * k1.w;
      }
    }
#pragma unroll
    for (int e = 0; e < 4; ++e) {
      float mx = s[e][0];
#pragma unroll
      for (int i = 1; i < 8; ++i) mx = fmaxf(mx, s[e][i]);
#pragma unroll
      for (int off = 32; off; off >>= 1) mx = fmaxf(mx, __shfl_xor(mx, off));
      float p[8], sum = 0.f;
#pragma unroll
      for (int i = 0; i < 8; ++i) { p[i] = __expf(0.25f * (s[e][i] - mx)); sum += p[i]; }
      float u0 = 0.f, u1 = 0.f, u2 = 0.f;
#pragma unroll
      for (int i = 0; i < 8; ++i) {
        u0 += p[i] * vwr[0][i];
        u1 += p[i] * vwr[1][i];
        u2 += p[i] * vwr[2][i];
      }
#pragma unroll
      for (int off = 32; off; off >>= 1) {
        sum += __shfl_xor(sum, off);
        u0  += __shfl_xor(u0, off);
        u1  += __shfl_xor(u1, off);
        u2  += __shfl_xor(u2, off);
      }
      if (lane == 0) {
        const float inv = 1.0f / sum;
        const size_t base = (size_t)b * 3 * 512 + (e0 + el0 + e);
        U[base]        = (_Float16)(u0 * inv);
        U[base + 512]  = (_Float16)(u1 * inv);
        U[base + 1024] = (_Float16)(u2 * inv);
      }
    }
  }
}

// ---------------------------------------------------------------------------
// Stage 3 (unchanged from R6): BM=192 (all M, Wo read once), BN=64.
// ---------------------------------------------------------------------------
__global__ __launch_bounds__(256) void out_gemm(
    const _Float16* __restrict__ U, const float* __restrict__ Wo,
    const float* __restrict__ x, const float* __restrict__ bo,
    const float* __restrict__ W3, float* __restrict__ outY)
{
  __shared__ _Float16 Au[2][192 * 32];  // 12 KB each
  __shared__ _Float16 Bw[2][64 * 32];   //  4 KB each
  const int t = threadIdx.x;
  const int wave = t >> 6, lane = t & 63;
  const int quad = lane >> 4, l16 = lane & 15;
  const int wr = wave >> 1, wc = wave & 1;       // 2 x 2 wave grid
  const int ntile = blockIdx.x;

  float w3s[3];
#pragma unroll
  for (int o = 0; o < 3; ++o) {
    float s = 0.f;
#pragma unroll
    for (int c = 0; c < 16; ++c) s += W3[o * 16 + c];
    w3s[o] = s;
  }

  const _Float16* auSrc[3];
  int auoff[3];
#pragma unroll
  for (int r = 0; r < 3; ++r) {
    const int un = t + r * 256;
    const int row = un >> 2, u = un & 3;
    const int sw = (row ^ (row >> 2)) & 3;
    auSrc[r] = U + (size_t)row * EE + u * 8;
    auoff[r] = row * 32 + ((u ^ sw) << 3);
  }
  const bool bAct = (t < 128);
  const int brow_s = t >> 1, bh = t & 1;
  const float* bSrc = Wo + (size_t)(ntile * 64 + brow_s) * EE + bh * 16;
  const int bswr = (brow_s ^ (brow_s >> 2)) & 3;
  const int boff0 = brow_s * 32 + ((((bh << 1) | 0) ^ bswr) << 3);
  const int boff1 = brow_s * 32 + ((((bh << 1) | 1) ^ bswr) << 3);

  floatx4 acc[6][2];
#pragma unroll
  for (int mr = 0; mr < 6; ++mr)
#pragma unroll
    for (int ct = 0; ct < 2; ++ct)
      acc[mr][ct] = (floatx4){0.f, 0.f, 0.f, 0.f};

  half8 lau0, lau1, lau2;
  float4 lb0, lb1, lb2, lb3;

  auto stage_load = [&](int kt_) {
    lau0 = *(const half8*)(auSrc[0] + kt_ * 32);
    lau1 = *(const half8*)(auSrc[1] + kt_ * 32);
    lau2 = *(const half8*)(auSrc[2] + kt_ * 32);
    if (bAct) {
      const float* bp = bSrc + kt_ * 32;
      lb0 = *(const float4*)(bp);
      lb1 = *(const float4*)(bp + 4);
      lb2 = *(const float4*)(bp + 8);
      lb3 = *(const float4*)(bp + 12);
    }
  };
  auto stage_write = [&](int buf_) {
    *(half8*)&Au[buf_][auoff[0]] = lau0;
    *(half8*)&Au[buf_][auoff[1]] = lau1;
    *(half8*)&Au[buf_][auoff[2]] = lau2;
    if (bAct) {
      *(half8*)&Bw[buf_][boff0] = cvt_half8(lb0, lb1);
      *(half8*)&Bw[buf_][boff1] = cvt_half8(lb2, lb3);
    }
  };
  auto compute = [&](int buf_) {
    half8 hb[2];
#pragma unroll
    for (int ct = 0; ct < 2; ++ct) {
      const int br = wc * 32 + ct * 16 + l16;
      const int sb = (br ^ (br >> 2)) & 3;
      hb[ct] = *(const half8*)&Bw[buf_][br * 32 + ((quad ^ sb) << 3)];
    }
#pragma unroll
    for (int mr = 0; mr < 6; ++mr) {
      const int ar = wr * 96 + mr * 16 + l16;
      const int sa = (ar ^ (ar >> 2)) & 3;
      const half8 ha = *(const half8*)&Au[buf_][ar * 32 + ((quad ^ sa) << 3)];
#pragma unroll
      for (int ct = 0; ct < 2; ++ct)
        acc[mr][ct] = __builtin_amdgcn_mfma_f32_16x16x32_f16(ha, hb[ct], acc[mr][ct], 0, 0, 0);
    }
  };

  stage_load(0);
  stage_write(0);
  __syncthreads();
  int cur = 0;
  for (int kt = 0; kt < 16; ++kt) {
    if (kt + 1 < 16) stage_load(kt + 1);
    compute(cur);
    if (kt + 1 < 16) {
      stage_write(cur ^ 1);
      __syncthreads();
      cur ^= 1;
    }
  }

#pragma unroll
  for (int mr = 0; mr < 6; ++mr) {
#pragma unroll
    for (int ct = 0; ct < 2; ++ct) {
      const int tc = ntile * 64 + wc * 32 + ct * 16 + l16;
      const float bot = bo[tc];
#pragma unroll
      for (int rg = 0; rg < 4; ++rg) {
        const int rr = wr * 96 + mr * 16 + quad * 4 + rg;
        const int bb = rr / 3, oo = rr - bb * 3;
        const float v = acc[mr][ct][rg]
                      + x[(size_t)(bb * 7 + oo) * TT + tc]
                      + w3s[oo] * bot;
        outY[(size_t)rr * TT + tc] = v;
      }
    }
  }
}

extern "C" void kernel_launch(void* const* d_in, const int* in_sizes, int n_in,
                              void* d_out, int out_size, void* d_ws, size_t ws_size,
                              hipStream_t stream) {
  const float* x  = (const float*)d_in[0];
  const float* W1 = (const float*)d_in[1];
  const float* W2 = (const float*)d_in[2];
  const float* Wq = (const float*)d_in[3];
  const float* bq = (const float*)d_in[4];
  const float* Wk = (const float*)d_in[5];
  const float* bk = (const float*)d_in[6];
  const float* Wv = (const float*)d_in[7];
  const float* bv = (const float*)d_in[8];
  const float* Wo = (const float*)d_in[9];
  const float* bo = (const float*)d_in[10];
  const float* W3 = (const float*)d_in[11];
  float* out = (float*)d_out;

  char* ws = (char*)d_ws;
  float* Xq      = (float*)ws;                  // 192*512  fp32 = 393216 B
  float* Xkv     = (float*)(ws + 393216);       // 256*1024 fp32 = 1048576 B
  _Float16* U    = (_Float16*)(ws + 1441792);   // 192*512  fp16 = 196608 B
  _Float16* P    = (_Float16*)(ws + 1638400);   // CH planes x 360448 fp16

  // pick split-K chunk count by available workspace (fp16 planes: 720 KB ea)
  int CH = 32;
  while (CH > 4 && ws_size < 1638400ull + (size_t)CH * PSZ * 2) CH >>= 1;
  const int KL = 16384 / CH;                    // K per chunk
  const int NT = KL / 32;                       // k-tiles per block
  const int nblk = 6 * CH;                      // divisible by 8 for all CH
  const int cpx = nblk / 8;

  // merged projections -> fp16 partial planes (no atomics)
  proj_gemm<<<dim3(nblk), 1024, 0, stream>>>(x, Wq, Wk, Wv, P, KL, NT, cpx);
  // sum CH planes -> Xq, Xkv (fp32)
  reduce_p<<<dim3(176), 256, 0, stream>>>(P, Xq, Xkv, CH);
  // attention middle -> U (192 x 512 fp16)
  attn_mid<<<dim3(8, BB), 256, 0, stream>>>(Xq, Xkv, W1, W2, W3, bq, bk, bv, U);
  // final projection + residual + bias
  out_gemm<<<dim3(256), 256, 0, stream>>>(U, Wo, x, bo, W3, out);
}